// Round 4
// baseline (234.690 us; speedup 1.0000x reference)
//
#include <hip/hip_runtime.h>

// TeacherEmbeddingTransform: block-diagonal GEMM, fp32.
//   x: (16384, 2304), weight: (25600,1) flat, bias: (576,), out: (16384, 576)
//   Blocks: 16x [16->4], 32x [32->8], 16x [64->16]
// 36 chunks of 64 in-cols -> 16 out-cols each (g1: 4x16->4, g2: 2x32->8,
// g3: 1x64->16). HBM floor: 151 MB read + 38 MB write ~= 30 us at 6.3 TB/s.
//
// v3: per-WAVE-private x tiles. wg = 128 thr = 2 waves; each wave owns a
// 64-row x 64-col LDS tile and computes ALL 16 out cols for its rows
// (lane = row, 16 accumulators). Consequences vs v2:
//   - x LDS read traffic 4x -> 1x (each element read once per wave)
//   - weights: shared 4 KB densified tile, wave-uniform b128 broadcasts
//   - NO barrier between staging and compute (same-wave dep, waitcnt only;
//     single __syncthreads covers only the shared weight tile)
//   - LDS 39 KB/wg -> 4 wg/CU = 8 waves/CU, each with 16 outstanding 1-KB
//     loads (demand ~2.3x HBM supply -> BW-limited, as intended)

#define BATCH   16384
#define IN_DIM  2304
#define OUT_DIM 576
#define CHUNKS  36
#define XS_LDW  68   // 64 + 4 pad (16-B aligned rows, canonical b128 pad)

__global__ __launch_bounds__(128) void fused_block_mm(
    const float* __restrict__ x, const float* __restrict__ w,
    const float* __restrict__ bias, float* __restrict__ out)
{
    __shared__ float wd[64 * 16];            // densified weights, k-major
    __shared__ float xs[2][64 * XS_LDW];     // per-wave private x tiles

    const int tid = threadIdx.x;
    const int bx  = blockIdx.x;
    const int cj  = bx % CHUNKS;             // chunk id (uniform)
    const int rt  = bx / CHUNKS;             // 128-row tile id, 0..127

    // ---- densify this chunk's weights into wd[64][16] (verified in v2) ----
    if (cj < 4) {                            // group 1: 4 blocks of 16->4
        const int wbase = cj * 256;
        #pragma unroll
        for (int i = 0; i < 8; ++i) {
            const int e = tid + i * 128, k = e >> 4, c = e & 15, b = k >> 4;
            wd[e] = ((c >> 2) == b)
                  ? w[wbase + b * 64 + ((k & 15) << 2) + (c & 3)] : 0.0f;
        }
    } else if (cj < 20) {                    // group 2: 2 blocks of 32->8
        const int wbase = 1024 + (cj - 4) * 512;
        #pragma unroll
        for (int i = 0; i < 8; ++i) {
            const int e = tid + i * 128, k = e >> 4, c = e & 15, b = k >> 5;
            wd[e] = ((c >> 3) == b)
                  ? w[wbase + b * 256 + ((k & 31) << 3) + (c & 7)] : 0.0f;
        }
    } else {                                 // group 3: dense 64->16 block
        const int wbase = 9216 + (cj - 20) * 1024;
        #pragma unroll
        for (int i = 0; i < 8; ++i) {
            const int e = tid + i * 128;
            wd[e] = w[wbase + e];
        }
    }
    __syncthreads();                         // only barrier: wd visibility

    const int wv   = tid >> 6;               // wave id 0/1
    const int lane = tid & 63;               // = row within wave tile
    float* __restrict__ xsw = xs[wv];
    const int row0 = rt * 128 + wv * 64;

    // ---- stage wave-private x tile: 64 rows x 64 cols, coalesced float4 ----
    const float* __restrict__ xsrc = x + (size_t)row0 * IN_DIM + cj * 64;
    #pragma unroll
    for (int i = 0; i < 16; ++i) {
        const int f = (i << 6) + lane;       // 1024 float4s total
        const int r = f >> 4, c = (f & 15) << 2;
        const float4 v = *reinterpret_cast<const float4*>(
            xsrc + (size_t)r * IN_DIM + c);
        *reinterpret_cast<float4*>(&xsw[r * XS_LDW + c]) = v;
    }
    // no __syncthreads: tile is wave-private; compiler emits waitcnt for the
    // same-wave ds_write -> ds_read dependency.

    // ---- compute: lane = row, 16 accumulators = all 16 out cols ----
    const int ocol = cj * 16;
    float4 a0 = *reinterpret_cast<const float4*>(&bias[ocol + 0]);
    float4 a1 = *reinterpret_cast<const float4*>(&bias[ocol + 4]);
    float4 a2 = *reinterpret_cast<const float4*>(&bias[ocol + 8]);
    float4 a3 = *reinterpret_cast<const float4*>(&bias[ocol + 12]);

    const int xb = lane * XS_LDW;
    #pragma unroll
    for (int k4 = 0; k4 < 16; ++k4) {
        const float4 xv = *reinterpret_cast<const float4*>(&xsw[xb + (k4 << 2)]);
        #pragma unroll
        for (int j = 0; j < 4; ++j) {
            const float xj = j == 0 ? xv.x : j == 1 ? xv.y : j == 2 ? xv.z : xv.w;
            const float* __restrict__ wr = &wd[((k4 << 2) + j) << 4];
            const float4 w0 = *reinterpret_cast<const float4*>(wr + 0);
            const float4 w1 = *reinterpret_cast<const float4*>(wr + 4);
            const float4 w2 = *reinterpret_cast<const float4*>(wr + 8);
            const float4 w3 = *reinterpret_cast<const float4*>(wr + 12);
            a0.x += xj * w0.x; a0.y += xj * w0.y; a0.z += xj * w0.z; a0.w += xj * w0.w;
            a1.x += xj * w1.x; a1.y += xj * w1.y; a1.z += xj * w1.z; a1.w += xj * w1.w;
            a2.x += xj * w2.x; a2.y += xj * w2.y; a2.z += xj * w2.z; a2.w += xj * w2.w;
            a3.x += xj * w3.x; a3.y += xj * w3.y; a3.z += xj * w3.z; a3.w += xj * w3.w;
        }
    }

    // ---- store: 64 contiguous bytes per lane ----
    float* __restrict__ op = out + (size_t)(row0 + lane) * OUT_DIM + ocol;
    reinterpret_cast<float4*>(op)[0] = a0;
    reinterpret_cast<float4*>(op)[1] = a1;
    reinterpret_cast<float4*>(op)[2] = a2;
    reinterpret_cast<float4*>(op)[3] = a3;
}

extern "C" void kernel_launch(void* const* d_in, const int* in_sizes, int n_in,
                              void* d_out, int out_size, void* d_ws, size_t ws_size,
                              hipStream_t stream) {
    const float* x    = (const float*)d_in[0];
    const float* w    = (const float*)d_in[1];
    const float* bias = (const float*)d_in[2];
    float* out        = (float*)d_out;

    // 36 chunks x (16384/128 = 128) row tiles; bx%36 keeps chunk-adjacent
    // wgs on the same rows (write-line merging + x row reuse in L2/L3)
    fused_block_mm<<<dim3(CHUNKS * 128), 128, 0, stream>>>(x, w, bias, out);
}